// Round 1
// baseline (332.348 us; speedup 1.0000x reference)
//
#include <hip/hip_runtime.h>
#include <cstdint>
#include <cstddef>

#define PASSA_EDGES 8192
#define PASSB_CAP   12288   // LDS csr-image capacity (ints); max bucket ~8700 for this input

// ---------------- bf16 helpers ----------------

__device__ __forceinline__ unsigned short f2bf(float f) {  // RNE
    unsigned int u = __float_as_uint(f);
    u += 0x7FFFu + ((u >> 16) & 1u);
    return (unsigned short)(u >> 16);
}

// fma 8 bf16 (packed in uint4) * w into acc[8]
__device__ __forceinline__ void bf8_fma(uint4 u, float w, float* acc) {
    acc[0] += __uint_as_float(u.x << 16) * w;
    acc[1] += __uint_as_float(u.x & 0xFFFF0000u) * w;
    acc[2] += __uint_as_float(u.y << 16) * w;
    acc[3] += __uint_as_float(u.y & 0xFFFF0000u) * w;
    acc[4] += __uint_as_float(u.z << 16) * w;
    acc[5] += __uint_as_float(u.z & 0xFFFF0000u) * w;
    acc[6] += __uint_as_float(u.w << 16) * w;
    acc[7] += __uint_as_float(u.w & 0xFFFF0000u) * w;
}
__device__ __forceinline__ void bf8_unpack(uint4 u, float* v) {
    v[0] = __uint_as_float(u.x << 16);
    v[1] = __uint_as_float(u.x & 0xFFFF0000u);
    v[2] = __uint_as_float(u.y << 16);
    v[3] = __uint_as_float(u.y & 0xFFFF0000u);
    v[4] = __uint_as_float(u.z << 16);
    v[5] = __uint_as_float(u.z & 0xFFFF0000u);
    v[6] = __uint_as_float(u.w << 16);
    v[7] = __uint_as_float(u.w & 0xFFFF0000u);
}

// ---------------- bucket cursor init ----------------

__global__ void bcur_init(int* __restrict__ bcur, int NBUCK, int CAP) {
    int b = threadIdx.x;
    if (b < NBUCK) bcur[b] = b * CAP;
}

// ---------------- pass A: bin (src,dst) by coarse dst bucket into slabs ----------------

__global__ __launch_bounds__(256) void passA(const int* __restrict__ src,
                                             const int* __restrict__ dst,
                                             int* __restrict__ bcur,
                                             int2* __restrict__ bbuf, int E,
                                             int CAP, int shift) {
    __shared__ int2 bins[PASSA_EDGES];
    __shared__ int  cnt[256], off[256], cur[256], gbase[256];
    const int t  = threadIdx.x;
    const int e0 = blockIdx.x * PASSA_EDGES;
    const int n  = min(PASSA_EDGES, E - e0);

    cnt[t] = 0;
    __syncthreads();
    for (int i = t; i < n; i += 256) atomicAdd(&cnt[dst[e0 + i] >> shift], 1);
    __syncthreads();

    int v = cnt[t];
    off[t] = v;
    __syncthreads();
    for (int o = 1; o < 256; o <<= 1) {
        int u = (t >= o) ? off[t - o] : 0;
        __syncthreads();
        off[t] += u;
        __syncthreads();
    }
    int excl = off[t] - v;
    off[t]   = excl;
    cur[t]   = excl;
    __syncthreads();

    for (int i = t; i < n; i += 256) {
        int d = dst[e0 + i];
        int s = src[e0 + i];
        int p = atomicAdd(&cur[d >> shift], 1);
        bins[p] = make_int2(s, d);
    }
    if (cnt[t] > 0) gbase[t] = atomicAdd(&bcur[t], cnt[t]);
    __syncthreads();

    const int w = t >> 6, lane = t & 63;
    for (int b = w; b < 256; b += 4) {
        int c = cnt[b];
        if (c == 0) continue;
        int lo  = off[b], go = gbase[b];
        int lim = (b + 1) * CAP;
        if (go + c > lim) c = max(0, lim - go);
        for (int i = lane; i < c; i += 64) bbuf[go + i] = bins[lo + i];
    }
}

// ---------------- per-bucket histogram + dis ----------------

__global__ __launch_bounds__(256) void hist_dis(const int2* __restrict__ bbuf,
                                                const int* __restrict__ bcur,
                                                int* __restrict__ hist,
                                                float* __restrict__ dis,
                                                int N, int CAP, int shift) {
    __shared__ int cnt[1024];
    const int b     = blockIdx.x;
    const int node0 = b << shift;
    const int nn    = min(1 << shift, N - node0);
    for (int j = threadIdx.x; j < nn; j += 256) cnt[j] = 0;
    __syncthreads();
    const int start = b * CAP, end = bcur[b];
    for (int e = start + threadIdx.x; e < end; e += 256)
        atomicAdd(&cnt[bbuf[e].y - node0], 1);
    __syncthreads();
    for (int j = threadIdx.x; j < nn; j += 256) {
        int c = cnt[j];
        hist[node0 + j] = c;
        dis[node0 + j]  = rsqrtf((float)(c + 1));  // +1 self loop
    }
}

// ---------------- 3-phase exclusive scan hist[0..N) -> ptr[0..N] ----------------

__global__ __launch_bounds__(256) void scan_partial(const int* __restrict__ hist,
                                                    int* __restrict__ partials, int N) {
    __shared__ int red[256];
    const int t    = threadIdx.x;
    const int base = blockIdx.x * 1024 + t * 4;
    int s = 0;
    if (base + 3 < N) {
        int4 v = *(const int4*)&hist[base];
        s = v.x + v.y + v.z + v.w;
    } else {
        for (int i = 0; i < 4; i++)
            if (base + i < N) s += hist[base + i];
    }
    red[t] = s;
    __syncthreads();
    for (int off = 128; off; off >>= 1) {
        if (t < off) red[t] += red[t + off];
        __syncthreads();
    }
    if (t == 0) partials[blockIdx.x] = red[0];
}

__global__ __launch_bounds__(256) void scan_offsets(int* __restrict__ partials, int NB) {
    __shared__ int tmp[256];
    const int t = threadIdx.x;
    int v = (t < NB) ? partials[t] : 0;
    tmp[t] = v;
    __syncthreads();
    for (int off = 1; off < 256; off <<= 1) {
        int u = (t >= off) ? tmp[t - off] : 0;
        __syncthreads();
        tmp[t] += u;
        __syncthreads();
    }
    if (t < NB) partials[t] = tmp[t] - v;
}

__global__ __launch_bounds__(256) void scan_apply(const int* __restrict__ hist,
                                                  const int* __restrict__ partials,
                                                  int* __restrict__ ptr, int N) {
    __shared__ int tsum[256];
    const int t    = threadIdx.x;
    const int base = blockIdx.x * 1024 + t * 4;
    int v[4];
    int s = 0;
    for (int i = 0; i < 4; i++) {
        v[i] = (base + i < N) ? hist[base + i] : 0;
        s += v[i];
    }
    tsum[t] = s;
    __syncthreads();
    for (int off = 1; off < 256; off <<= 1) {
        int u = (t >= off) ? tsum[t - off] : 0;
        __syncthreads();
        tsum[t] += u;
        __syncthreads();
    }
    int run = partials[blockIdx.x] + tsum[t] - s;
    for (int i = 0; i < 4; i++) {
        if (base + i < N) {
            ptr[base + i] = run;
            run += v[i];
        }
    }
    if (base <= N - 1 && N - 1 < base + 4) ptr[N] = run;  // total = E
}

// ---------------- pass B: per-bucket LDS scatter -> contiguous (src,w) csr write ----
// csrw[e] = {src, bitcast(dis[src])}: pre-fusing the weight removes the dependent
// 64-way-divergent dis[src] gather from BOTH agg kernels (paid once here instead).

__global__ __launch_bounds__(256) void passB(const int2* __restrict__ bbuf,
                                             const int* __restrict__ bcur,
                                             const int* __restrict__ ptr,
                                             int2* __restrict__ csrw,
                                             const float* __restrict__ dis,
                                             int N, int CAP, int shift) {
    __shared__ int lcnt[1024];
    __shared__ int lcsr[PASSB_CAP];
    const int b     = blockIdx.x;
    const int node0 = b << shift;
    const int nn    = min(1 << shift, N - node0);
    const int cbase = ptr[node0];
    const int csize = ptr[node0 + nn] - cbase;

    for (int j = threadIdx.x; j < nn; j += 256) lcnt[j] = ptr[node0 + j] - cbase;
    __syncthreads();

    const int start = b * CAP, end = bcur[b];
    if (csize <= PASSB_CAP) {
        for (int e = start + threadIdx.x; e < end; e += 256) {
            int2 pr = bbuf[e];
            int  p  = atomicAdd(&lcnt[pr.y - node0], 1);
            lcsr[p] = pr.x;
        }
        __syncthreads();
        for (int i = threadIdx.x; i < csize; i += 256) {
            int s = lcsr[i];
            csrw[cbase + i] = make_int2(s, __float_as_int(dis[s]));
        }
    } else {  // fallback: direct global scatter
        for (int e = start + threadIdx.x; e < end; e += 256) {
            int2 pr = bbuf[e];
            int  p  = atomicAdd(&lcnt[pr.y - node0], 1);
            csrw[cbase + p] = make_int2(pr.x, __float_as_int(dis[pr.x]));
        }
    }
}

// ---------------- GEMM: Yb[N x 64](bf16) = X[N x K] @ W[K x 64] ----------------
// #pragma unroll 2 REQUIRED (full unroll -> 256 VGPR + scratch spill, R6).

template <int K>
__global__ __launch_bounds__(256) void gemm64_bf16(const float* __restrict__ X,
                                                   const float* __restrict__ W,
                                                   unsigned short* __restrict__ Yb, int N) {
    constexpr int LDX = K + 4;
    __shared__ float xs[64 * LDX];
    __shared__ float ws[K * 64];
    const int tid  = threadIdx.x;
    const int row0 = blockIdx.x * 64;

    const float4* W4 = (const float4*)W;
    for (int i = tid; i < K * 16; i += 256) ((float4*)ws)[i] = W4[i];

    const float4* X4  = (const float4*)(X + (size_t)row0 * K);
    const int     nf4 = (row0 < N ? min(64, N - row0) : 0) * (K / 4);
    for (int i = tid; i < 16 * K; i += 256) {
        float4 v = make_float4(0.f, 0.f, 0.f, 0.f);
        if (i < nf4) v = X4[i];
        int r  = i / (K / 4);
        int kk = (i % (K / 4)) * 4;
        *(float4*)&xs[r * LDX + kk] = v;
    }
    __syncthreads();

    const int cg = tid & 15;
    const int rg = tid >> 4;

    float acc[4][4] = {};
#pragma unroll 2
    for (int k = 0; k < K; k += 4) {
        float4 xf[4], wf[4];
#pragma unroll
        for (int i = 0; i < 4; i++) xf[i] = *(const float4*)&xs[(rg * 4 + i) * LDX + k];
#pragma unroll
        for (int j = 0; j < 4; j++) wf[j] = *(const float4*)&ws[(k + j) * 64 + cg * 4];
#pragma unroll
        for (int i = 0; i < 4; i++) {
            float4 xv = xf[i];
            acc[i][0] += xv.x * wf[0].x + xv.y * wf[1].x + xv.z * wf[2].x + xv.w * wf[3].x;
            acc[i][1] += xv.x * wf[0].y + xv.y * wf[1].y + xv.z * wf[2].y + xv.w * wf[3].y;
            acc[i][2] += xv.x * wf[0].z + xv.y * wf[1].z + xv.z * wf[2].z + xv.w * wf[3].z;
            acc[i][3] += xv.x * wf[0].w + xv.y * wf[1].w + xv.z * wf[2].w + xv.w * wf[3].w;
        }
    }

#pragma unroll
    for (int i = 0; i < 4; i++) {
        int r = row0 + rg * 4 + i;
        if (r < N) {
            ushort4 o;
            o.x = f2bf(acc[i][0]); o.y = f2bf(acc[i][1]);
            o.z = f2bf(acc[i][2]); o.w = f2bf(acc[i][3]);
            *(ushort4*)&Yb[(size_t)r * 64 + cg * 4] = o;
        }
    }
}

// ---------------- dual-row gather core ----------------
// Wave processes TWO rows at once to double outstanding B-row loads (4 -> 8).
// Lanes 0-31 load row-A's edge slab, lanes 32-63 row-B's; combined slot space
// [0,64): slots i*8+eg, i<4 -> accA, i>=4 -> accB. Per-lane accumulation order
// per row is IDENTICAL to the previous single-row kernel (slots eg,8+eg,16+eg,
// 24+eg) -> bitwise-same numerics. Overrun slots carry w=0 (row-0 loads, harmless).
// After the xor-reduce EVERY lane holds the full accA/accB for its channel octet.

__device__ __forceinline__ void gather8_dual(const unsigned short* __restrict__ B,
                                             const int2* __restrict__ csrw,
                                             int s0a, int s1a, int s0b, int s1b,
                                             int lane, int eg, int co,
                                             float* accA, float* accB) {
    const int sl = lane & 31;
    const int hi = lane >> 5;
    int basea = s0a, baseb = s0b;
    while (basea < s1a || baseb < s1b) {
        const int e   = (hi ? baseb : basea) + sl;
        const int lim = hi ? s1b : s1a;
        int   sv = 0;
        float wv = 0.f;
        if (e < lim) {
            int2 p = csrw[e];
            sv = p.x;
            wv = __int_as_float(p.y);
        }
        int   s_[8];
        float w_[8];
#pragma unroll
        for (int i = 0; i < 8; i++) {
            s_[i] = __shfl(sv, i * 8 + eg);
            w_[i] = __shfl(wv, i * 8 + eg);
        }
        uint4 u_[8];
#pragma unroll
        for (int i = 0; i < 8; i++)
            u_[i] = *(const uint4*)&B[(size_t)s_[i] * 64 + co * 8];
#pragma unroll
        for (int i = 0; i < 4; i++) bf8_fma(u_[i], w_[i], accA);
#pragma unroll
        for (int i = 4; i < 8; i++) bf8_fma(u_[i], w_[i], accB);
        basea += 32;
        baseb += 32;
    }
#pragma unroll
    for (int off = 8; off <= 32; off <<= 1)
#pragma unroll
        for (int i = 0; i < 8; i++) {
            accA[i] += __shfl_xor(accA[i], off);
            accB[i] += __shfl_xor(accB[i], off);
        }
}

// ---------------- layer-1 epilogue: self term + relu + fused gemm2 -> bf16 ----------
// gemm2 uses the R9 conflict-free mapping: lane=(eg2=lane>>4, cq=lane&15),
// k=eg2*16+j, W2 read at w2s[k*64+cq*4] (all 32 banks, 2-way = free).

__device__ __forceinline__ void l1_tail(const unsigned short* __restrict__ B,
                                        const float* w2s, const float* bb,
                                        int row, const float* acc, float di,
                                        int lane, int co, int eg2, int cq,
                                        unsigned short* __restrict__ hw) {
    uint4 us = *(const uint4*)&B[(size_t)row * 64 + co * 8];
    float bs[8];
    bf8_unpack(us, bs);
    float h[8];
#pragma unroll
    for (int i = 0; i < 8; i++)
        h[i] = fmaxf((acc[i] + bs[i] * di) * di + bb[i], 0.f);

    // fused gemm2: lane (eg2,cq) -> out channels cq*4..+3, k = eg2*16+j.
    // source lane holds channel k in h[k&7]; any lane with (lane&7)==k>>3.
    float o[4] = {0.f, 0.f, 0.f, 0.f};
#pragma unroll
    for (int j = 0; j < 16; j++) {
        const int k    = eg2 * 16 + j;
        const int srcl = (lane & 56) | (eg2 * 2 + (j >> 3));
        float     hk   = __shfl(h[j & 7], srcl);
        const float4 wr = *(const float4*)&w2s[k * 64 + cq * 4];
        o[0] += hk * wr.x;
        o[1] += hk * wr.y;
        o[2] += hk * wr.z;
        o[3] += hk * wr.w;
    }
#pragma unroll
    for (int off = 16; off <= 32; off <<= 1)
#pragma unroll
        for (int i = 0; i < 4; i++) o[i] += __shfl_xor(o[i], off);

    if (eg2 == 0) {
        ushort4 ob;
        ob.x = f2bf(o[0]); ob.y = f2bf(o[1]);
        ob.z = f2bf(o[2]); ob.w = f2bf(o[3]);
        *(ushort4*)&hw[(size_t)row * 64 + cq * 4] = ob;
    }
}

// ---------------- layer 1: dual-row pull-agg + relu + fused gemm2 -> bf16 hw --------

__global__ __launch_bounds__(256) void agg_l1(const unsigned short* __restrict__ B,
                                              const int2* __restrict__ csrw,
                                              const int* __restrict__ ptr,
                                              const float* __restrict__ dis,
                                              const float* __restrict__ b1,
                                              const float* __restrict__ W2,
                                              unsigned short* __restrict__ hw, int N) {
    __shared__ float w2s[64 * 64];
    for (int i = threadIdx.x; i < 1024; i += 256)
        ((float4*)w2s)[i] = ((const float4*)W2)[i];
    __syncthreads();

    const int wid  = threadIdx.x >> 6;
    const int lane = threadIdx.x & 63;
    const int eg   = lane >> 3;
    const int co   = lane & 7;
    const int eg2  = lane >> 4;
    const int cq   = lane & 15;

    float bb[8];
    *(float4*)&bb[0] = *(const float4*)&b1[co * 8];
    *(float4*)&bb[4] = *(const float4*)&b1[co * 8 + 4];

    const int rbase = blockIdx.x * 16 + wid * 4;
    for (int g = 0; g < 2; g++) {
        const int ra = rbase + g * 2;
        if (ra >= N) break;
        const int  rb = ra + 1;
        const bool hb = (rb < N);
        const int s0a = ptr[ra];
        const int s1a = ptr[ra + 1];                 // == ptr[rb] (contiguous rows)
        const int s1b = hb ? ptr[rb + 1] : s1a;
        const float diA = dis[ra];
        const float diB = hb ? dis[rb] : 0.f;

        float accA[8] = {}, accB[8] = {};
        gather8_dual(B, csrw, s0a, s1a, s1a, s1b, lane, eg, co, accA, accB);

        l1_tail(B, w2s, bb, ra, accA, diA, lane, co, eg2, cq, hw);
        if (hb) l1_tail(B, w2s, bb, rb, accB, diB, lane, co, eg2, cq, hw);
    }
}

// ---------------- layer-2 epilogue: self term + bias + log_softmax -> fp32 ----------

__device__ __forceinline__ void l2_tail(const unsigned short* __restrict__ B,
                                        const float* bb, int row, const float* acc,
                                        float di, int lane, int eg, int co,
                                        float* __restrict__ out) {
    uint4 us = *(const uint4*)&B[(size_t)row * 64 + co * 8];
    float bs[8];
    bf8_unpack(us, bs);
    float v[8];
#pragma unroll
    for (int i = 0; i < 8; i++) v[i] = (acc[i] + bs[i] * di) * di + bb[i];

    float m = v[0];
#pragma unroll
    for (int i = 1; i < 8; i++) m = fmaxf(m, v[i]);
#pragma unroll
    for (int off = 1; off <= 4; off <<= 1) m = fmaxf(m, __shfl_xor(m, off));
    float s = 0.f;
#pragma unroll
    for (int i = 0; i < 8; i++) s += __expf(v[i] - m);
#pragma unroll
    for (int off = 1; off <= 4; off <<= 1) s += __shfl_xor(s, off);
    float lse = m + __logf(s);

    if (eg == 0) {
        float4 oa = make_float4(v[0] - lse, v[1] - lse, v[2] - lse, v[3] - lse);
        float4 ob = make_float4(v[4] - lse, v[5] - lse, v[6] - lse, v[7] - lse);
        *(float4*)&out[(size_t)row * 64 + co * 8]     = oa;
        *(float4*)&out[(size_t)row * 64 + co * 8 + 4] = ob;
    }
}

// ---------------- layer 2: dual-row pull-agg + bias + log_softmax -> fp32 out -------

__global__ __launch_bounds__(256) void agg_l2(const unsigned short* __restrict__ B,
                                              const int2* __restrict__ csrw,
                                              const int* __restrict__ ptr,
                                              const float* __restrict__ dis,
                                              const float* __restrict__ b2,
                                              float* __restrict__ out, int N) {
    const int wid  = threadIdx.x >> 6;
    const int lane = threadIdx.x & 63;
    const int eg   = lane >> 3;
    const int co   = lane & 7;

    const int ra = blockIdx.x * 8 + wid * 2;
    if (ra >= N) return;
    const int  rb = ra + 1;
    const bool hb = (rb < N);

    float bb[8];
    *(float4*)&bb[0] = *(const float4*)&b2[co * 8];
    *(float4*)&bb[4] = *(const float4*)&b2[co * 8 + 4];

    const int s0a = ptr[ra];
    const int s1a = ptr[ra + 1];                     // == ptr[rb]
    const int s1b = hb ? ptr[rb + 1] : s1a;
    const float diA = dis[ra];
    const float diB = hb ? dis[rb] : 0.f;

    float accA[8] = {}, accB[8] = {};
    gather8_dual(B, csrw, s0a, s1a, s1a, s1b, lane, eg, co, accA, accB);

    l2_tail(B, bb, ra, accA, diA, lane, eg, co, out);
    if (hb) l2_tail(B, bb, rb, accB, diB, lane, eg, co, out);
}

// ---------------- launch ----------------

extern "C" void kernel_launch(void* const* d_in, const int* in_sizes, int n_in,
                              void* d_out, int out_size, void* d_ws, size_t ws_size,
                              hipStream_t stream) {
    const float* x   = (const float*)d_in[0];
    const int*   ei  = (const int*)d_in[1];
    const float* W1  = (const float*)d_in[2];
    const float* b1  = (const float*)d_in[3];
    const float* W2  = (const float*)d_in[4];
    const float* b2  = (const float*)d_in[5];
    float*       out = (float*)d_out;

    const int  N   = in_sizes[0] / 128;
    const int  E   = in_sizes[1] / 2;
    const int* src = ei;
    const int* dst = ei + E;
    const int  NB  = (N + 1023) / 1024;

    int shift = 9;
    while (((N - 1) >> shift) >= 256) shift++;
    const int NBUCK = ((N - 1) >> shift) + 1;
    const int CAP   = ((E / NBUCK) * 3 / 2 + 255) & ~255;

    auto align256 = [](size_t v) { return (v + 255) & ~(size_t)255; };
    char*           p        = (char*)d_ws;
    float*          dis      = (float*)p;          p += align256((size_t)N * 4);
    int*            ptr      = (int*)p;            p += align256((size_t)(N + 1) * 4);
    int*            hist     = (int*)p;            p += align256((size_t)N * 4);
    int*            partials = (int*)p;            p += align256((size_t)NB * 4);
    int*            bcur     = (int*)p;            p += align256(256 * 4);
    int2*           csrw     = (int2*)p;           p += align256((size_t)E * 8);
    int2*           bbuf     = (int2*)p;           p += align256((size_t)NBUCK * CAP * 8);
    unsigned short* xwb      = (unsigned short*)p; p += align256((size_t)N * 64 * 2);
    unsigned short* hwb      = (unsigned short*)p; p += align256((size_t)N * 64 * 2);

    bcur_init<<<1, 256, 0, stream>>>(bcur, NBUCK, CAP);
    passA<<<(E + PASSA_EDGES - 1) / PASSA_EDGES, 256, 0, stream>>>(src, dst, bcur, bbuf, E, CAP, shift);
    hist_dis<<<NBUCK, 256, 0, stream>>>(bbuf, bcur, hist, dis, N, CAP, shift);
    scan_partial<<<NB, 256, 0, stream>>>(hist, partials, N);
    scan_offsets<<<1, 256, 0, stream>>>(partials, NB);
    scan_apply<<<NB, 256, 0, stream>>>(hist, partials, ptr, N);
    passB<<<NBUCK, 256, 0, stream>>>(bbuf, bcur, ptr, csrw, dis, N, CAP, shift);

    gemm64_bf16<128><<<(N + 63) / 64, 256, 0, stream>>>(x, W1, xwb, N);
    agg_l1<<<(N + 15) / 16, 256, 0, stream>>>(xwb, csrw, ptr, dis, b1, W2, hwb, N);
    agg_l2<<<(N + 7) / 8, 256, 0, stream>>>(hwb, csrw, ptr, dis, b2, out, N);
}

// Round 2
// 289.469 us; speedup vs baseline: 1.1481x; 1.1481x over previous
//
#include <hip/hip_runtime.h>
#include <cstdint>
#include <cstddef>

#define PASSA_EDGES 8192
#define PASSB_CAP   12288   // LDS csr-image capacity (ints); max bucket ~8700 for this input

// ---------------- bf16 helpers ----------------

__device__ __forceinline__ unsigned short f2bf(float f) {  // RNE
    unsigned int u = __float_as_uint(f);
    u += 0x7FFFu + ((u >> 16) & 1u);
    return (unsigned short)(u >> 16);
}

// fma 8 bf16 (packed in uint4) * w into acc[8]
__device__ __forceinline__ void bf8_fma(uint4 u, float w, float* acc) {
    acc[0] += __uint_as_float(u.x << 16) * w;
    acc[1] += __uint_as_float(u.x & 0xFFFF0000u) * w;
    acc[2] += __uint_as_float(u.y << 16) * w;
    acc[3] += __uint_as_float(u.y & 0xFFFF0000u) * w;
    acc[4] += __uint_as_float(u.z << 16) * w;
    acc[5] += __uint_as_float(u.z & 0xFFFF0000u) * w;
    acc[6] += __uint_as_float(u.w << 16) * w;
    acc[7] += __uint_as_float(u.w & 0xFFFF0000u) * w;
}
__device__ __forceinline__ void bf8_unpack(uint4 u, float* v) {
    v[0] = __uint_as_float(u.x << 16);
    v[1] = __uint_as_float(u.x & 0xFFFF0000u);
    v[2] = __uint_as_float(u.y << 16);
    v[3] = __uint_as_float(u.y & 0xFFFF0000u);
    v[4] = __uint_as_float(u.z << 16);
    v[5] = __uint_as_float(u.z & 0xFFFF0000u);
    v[6] = __uint_as_float(u.w << 16);
    v[7] = __uint_as_float(u.w & 0xFFFF0000u);
}

// ---------------- bucket cursor init ----------------

__global__ void bcur_init(int* __restrict__ bcur, int NBUCK, int CAP) {
    int b = threadIdx.x;
    if (b < NBUCK) bcur[b] = b * CAP;
}

// ---------------- pass A: bin (src,dst) by coarse dst bucket into slabs ----------------

__global__ __launch_bounds__(256) void passA(const int* __restrict__ src,
                                             const int* __restrict__ dst,
                                             int* __restrict__ bcur,
                                             int2* __restrict__ bbuf, int E,
                                             int CAP, int shift) {
    __shared__ int2 bins[PASSA_EDGES];
    __shared__ int  cnt[256], off[256], cur[256], gbase[256];
    const int t  = threadIdx.x;
    const int e0 = blockIdx.x * PASSA_EDGES;
    const int n  = min(PASSA_EDGES, E - e0);

    cnt[t] = 0;
    __syncthreads();
    for (int i = t; i < n; i += 256) atomicAdd(&cnt[dst[e0 + i] >> shift], 1);
    __syncthreads();

    int v = cnt[t];
    off[t] = v;
    __syncthreads();
    for (int o = 1; o < 256; o <<= 1) {
        int u = (t >= o) ? off[t - o] : 0;
        __syncthreads();
        off[t] += u;
        __syncthreads();
    }
    int excl = off[t] - v;
    off[t]   = excl;
    cur[t]   = excl;
    __syncthreads();

    for (int i = t; i < n; i += 256) {
        int d = dst[e0 + i];
        int s = src[e0 + i];
        int p = atomicAdd(&cur[d >> shift], 1);
        bins[p] = make_int2(s, d);
    }
    if (cnt[t] > 0) gbase[t] = atomicAdd(&bcur[t], cnt[t]);
    __syncthreads();

    const int w = t >> 6, lane = t & 63;
    for (int b = w; b < 256; b += 4) {
        int c = cnt[b];
        if (c == 0) continue;
        int lo  = off[b], go = gbase[b];
        int lim = (b + 1) * CAP;
        if (go + c > lim) c = max(0, lim - go);
        for (int i = lane; i < c; i += 64) bbuf[go + i] = bins[lo + i];
    }
}

// ---------------- per-bucket histogram + dis ----------------

__global__ __launch_bounds__(256) void hist_dis(const int2* __restrict__ bbuf,
                                                const int* __restrict__ bcur,
                                                int* __restrict__ hist,
                                                float* __restrict__ dis,
                                                int N, int CAP, int shift) {
    __shared__ int cnt[1024];
    const int b     = blockIdx.x;
    const int node0 = b << shift;
    const int nn    = min(1 << shift, N - node0);
    for (int j = threadIdx.x; j < nn; j += 256) cnt[j] = 0;
    __syncthreads();
    const int start = b * CAP, end = bcur[b];
    for (int e = start + threadIdx.x; e < end; e += 256)
        atomicAdd(&cnt[bbuf[e].y - node0], 1);
    __syncthreads();
    for (int j = threadIdx.x; j < nn; j += 256) {
        int c = cnt[j];
        hist[node0 + j] = c;
        dis[node0 + j]  = rsqrtf((float)(c + 1));  // +1 self loop
    }
}

// ---------------- 3-phase exclusive scan hist[0..N) -> ptr[0..N] ----------------

__global__ __launch_bounds__(256) void scan_partial(const int* __restrict__ hist,
                                                    int* __restrict__ partials, int N) {
    __shared__ int red[256];
    const int t    = threadIdx.x;
    const int base = blockIdx.x * 1024 + t * 4;
    int s = 0;
    if (base + 3 < N) {
        int4 v = *(const int4*)&hist[base];
        s = v.x + v.y + v.z + v.w;
    } else {
        for (int i = 0; i < 4; i++)
            if (base + i < N) s += hist[base + i];
    }
    red[t] = s;
    __syncthreads();
    for (int off = 128; off; off >>= 1) {
        if (t < off) red[t] += red[t + off];
        __syncthreads();
    }
    if (t == 0) partials[blockIdx.x] = red[0];
}

__global__ __launch_bounds__(256) void scan_offsets(int* __restrict__ partials, int NB) {
    __shared__ int tmp[256];
    const int t = threadIdx.x;
    int v = (t < NB) ? partials[t] : 0;
    tmp[t] = v;
    __syncthreads();
    for (int off = 1; off < 256; off <<= 1) {
        int u = (t >= off) ? tmp[t - off] : 0;
        __syncthreads();
        tmp[t] += u;
        __syncthreads();
    }
    if (t < NB) partials[t] = tmp[t] - v;
}

__global__ __launch_bounds__(256) void scan_apply(const int* __restrict__ hist,
                                                  const int* __restrict__ partials,
                                                  int* __restrict__ ptr, int N) {
    __shared__ int tsum[256];
    const int t    = threadIdx.x;
    const int base = blockIdx.x * 1024 + t * 4;
    int v[4];
    int s = 0;
    for (int i = 0; i < 4; i++) {
        v[i] = (base + i < N) ? hist[base + i] : 0;
        s += v[i];
    }
    tsum[t] = s;
    __syncthreads();
    for (int off = 1; off < 256; off <<= 1) {
        int u = (t >= off) ? tsum[t - off] : 0;
        __syncthreads();
        tsum[t] += u;
        __syncthreads();
    }
    int run = partials[blockIdx.x] + tsum[t] - s;
    for (int i = 0; i < 4; i++) {
        if (base + i < N) {
            ptr[base + i] = run;
            run += v[i];
        }
    }
    if (base <= N - 1 && N - 1 < base + 4) ptr[N] = run;  // total = E
}

// ---------------- pass B: per-bucket LDS scatter -> contiguous (src,w) csr write ----
// csrw[e] = {src, bitcast(dis[src])}: pre-fusing the weight removes the dependent
// 64-way-divergent dis[src] gather from BOTH agg kernels (paid once here instead).

__global__ __launch_bounds__(256) void passB(const int2* __restrict__ bbuf,
                                             const int* __restrict__ bcur,
                                             const int* __restrict__ ptr,
                                             int2* __restrict__ csrw,
                                             const float* __restrict__ dis,
                                             int N, int CAP, int shift) {
    __shared__ int lcnt[1024];
    __shared__ int lcsr[PASSB_CAP];
    const int b     = blockIdx.x;
    const int node0 = b << shift;
    const int nn    = min(1 << shift, N - node0);
    const int cbase = ptr[node0];
    const int csize = ptr[node0 + nn] - cbase;

    for (int j = threadIdx.x; j < nn; j += 256) lcnt[j] = ptr[node0 + j] - cbase;
    __syncthreads();

    const int start = b * CAP, end = bcur[b];
    if (csize <= PASSB_CAP) {
        for (int e = start + threadIdx.x; e < end; e += 256) {
            int2 pr = bbuf[e];
            int  p  = atomicAdd(&lcnt[pr.y - node0], 1);
            lcsr[p] = pr.x;
        }
        __syncthreads();
        for (int i = threadIdx.x; i < csize; i += 256) {
            int s = lcsr[i];
            csrw[cbase + i] = make_int2(s, __float_as_int(dis[s]));
        }
    } else {  // fallback: direct global scatter
        for (int e = start + threadIdx.x; e < end; e += 256) {
            int2 pr = bbuf[e];
            int  p  = atomicAdd(&lcnt[pr.y - node0], 1);
            csrw[cbase + p] = make_int2(pr.x, __float_as_int(dis[pr.x]));
        }
    }
}

// ---------------- GEMM: Yb[N x 64](bf16) = X[N x K] @ W[K x 64] ----------------
// #pragma unroll 2 REQUIRED (full unroll -> 256 VGPR + scratch spill, R6).

template <int K>
__global__ __launch_bounds__(256) void gemm64_bf16(const float* __restrict__ X,
                                                   const float* __restrict__ W,
                                                   unsigned short* __restrict__ Yb, int N) {
    constexpr int LDX = K + 4;
    __shared__ float xs[64 * LDX];
    __shared__ float ws[K * 64];
    const int tid  = threadIdx.x;
    const int row0 = blockIdx.x * 64;

    const float4* W4 = (const float4*)W;
    for (int i = tid; i < K * 16; i += 256) ((float4*)ws)[i] = W4[i];

    const float4* X4  = (const float4*)(X + (size_t)row0 * K);
    const int     nf4 = (row0 < N ? min(64, N - row0) : 0) * (K / 4);
    for (int i = tid; i < 16 * K; i += 256) {
        float4 v = make_float4(0.f, 0.f, 0.f, 0.f);
        if (i < nf4) v = X4[i];
        int r  = i / (K / 4);
        int kk = (i % (K / 4)) * 4;
        *(float4*)&xs[r * LDX + kk] = v;
    }
    __syncthreads();

    const int cg = tid & 15;
    const int rg = tid >> 4;

    float acc[4][4] = {};
#pragma unroll 2
    for (int k = 0; k < K; k += 4) {
        float4 xf[4], wf[4];
#pragma unroll
        for (int i = 0; i < 4; i++) xf[i] = *(const float4*)&xs[(rg * 4 + i) * LDX + k];
#pragma unroll
        for (int j = 0; j < 4; j++) wf[j] = *(const float4*)&ws[(k + j) * 64 + cg * 4];
#pragma unroll
        for (int i = 0; i < 4; i++) {
            float4 xv = xf[i];
            acc[i][0] += xv.x * wf[0].x + xv.y * wf[1].x + xv.z * wf[2].x + xv.w * wf[3].x;
            acc[i][1] += xv.x * wf[0].y + xv.y * wf[1].y + xv.z * wf[2].y + xv.w * wf[3].y;
            acc[i][2] += xv.x * wf[0].z + xv.y * wf[1].z + xv.z * wf[2].z + xv.w * wf[3].z;
            acc[i][3] += xv.x * wf[0].w + xv.y * wf[1].w + xv.z * wf[2].w + xv.w * wf[3].w;
        }
    }

#pragma unroll
    for (int i = 0; i < 4; i++) {
        int r = row0 + rg * 4 + i;
        if (r < N) {
            ushort4 o;
            o.x = f2bf(acc[i][0]); o.y = f2bf(acc[i][1]);
            o.z = f2bf(acc[i][2]); o.w = f2bf(acc[i][3]);
            *(ushort4*)&Yb[(size_t)r * 64 + cg * 4] = o;
        }
    }
}

// ---------------- oct-row gather core: 8 rows/wave, group-per-row ----------------
// Group eg (8 lanes, co=0..7) owns ONE row: its slab slots are its own lanes
// (slot i = edge s0+it*8+i), broadcast via GROUP-LOCAL shuffles (srcl=(lane&56)|i).
// Consequences vs the old dual-row core:
//   * zero cross-lane reduce: all of a row's edges flow through its group, so each
//     lane ends holding the finished sum for its channel octet.
//   * groups exit the loop independently (divergence is safe: shuffles never cross
//     groups; exec-masked lanes issue no loads) -> slot waste ~20% instead of ~50%.
//   * per-iteration MLP unchanged: 8 independent row-line loads in flight; the
//     next slab chunk is prefetched before the FMA block so its latency hides.
// Overrun slots in the last iteration carry w=0 (row-0 loads, L1-hit, harmless).

__device__ __forceinline__ void gather8_oct(const unsigned short* __restrict__ B,
                                            const int2* __restrict__ csrw,
                                            int s0, int s1, int iters,
                                            int lane, int co, float* acc) {
    int  e  = s0 + co;
    int2 pv = make_int2(0, 0);
    if (e < s1) pv = csrw[e];
    for (int it = 0; it < iters; ++it) {
        const int en = e + 8;
        int2      pn = make_int2(0, 0);
        if (it + 1 < iters && en < s1) pn = csrw[en];  // prefetch next slab chunk
        const int   sv = pv.x;
        const float wv = __int_as_float(pv.y);
        int   s_[8];
        float w_[8];
#pragma unroll
        for (int i = 0; i < 8; i++) {
            const int srcl = (lane & 56) | i;  // group-local broadcast
            s_[i] = __shfl(sv, srcl);
            w_[i] = __shfl(wv, srcl);
        }
        uint4 u_[8];
#pragma unroll
        for (int i = 0; i < 8; i++)
            u_[i] = *(const uint4*)&B[(size_t)s_[i] * 64 + co * 8];
#pragma unroll
        for (int i = 0; i < 8; i++) bf8_fma(u_[i], w_[i], acc);
        pv = pn;
        e  = en;
    }
}

// ---------------- layer 1: oct-row pull-agg + relu + fused gemm2 -> bf16 hw --------
// gemm2 keeps the R9 conflict-free W2 mapping (lane=(eg2,cq), k=eg2*16+j, float4 at
// w2s[k*64+cq*4]); hk now comes from row r's OWN group via
// srcl = r*8 + (k>>3) = r*8 + eg2*2 + (j>>3), element k&7 = j&7.

__global__ __launch_bounds__(256) void agg_l1(const unsigned short* __restrict__ B,
                                              const int2* __restrict__ csrw,
                                              const int* __restrict__ ptr,
                                              const float* __restrict__ dis,
                                              const float* __restrict__ b1,
                                              const float* __restrict__ W2,
                                              unsigned short* __restrict__ hw, int N) {
    __shared__ float w2s[64 * 64];
    for (int i = threadIdx.x; i < 1024; i += 256)
        ((float4*)w2s)[i] = ((const float4*)W2)[i];
    __syncthreads();

    const int wid  = threadIdx.x >> 6;
    const int lane = threadIdx.x & 63;
    const int eg   = lane >> 3;
    const int co   = lane & 7;
    const int eg2  = lane >> 4;
    const int cq   = lane & 15;

    const int  rbase = blockIdx.x * 32 + wid * 8;
    const int  row   = rbase + eg;   // group eg owns this row
    const bool hr    = (row < N);

    const int   s0 = hr ? ptr[row] : 0;
    const int   s1 = hr ? ptr[row + 1] : 0;
    const float di = hr ? dis[row] : 0.f;
    const int   iters = (s1 - s0 + 7) >> 3;

    float acc[8] = {};
    gather8_oct(B, csrw, s0, s1, iters, lane, co, acc);

    float h[8] = {};
    if (hr) {
        uint4 us = *(const uint4*)&B[(size_t)row * 64 + co * 8];
        float bs[8];
        bf8_unpack(us, bs);
        float bb[8];
        *(float4*)&bb[0] = *(const float4*)&b1[co * 8];
        *(float4*)&bb[4] = *(const float4*)&b1[co * 8 + 4];
#pragma unroll
        for (int i = 0; i < 8; i++)
            h[i] = fmaxf((acc[i] + bs[i] * di) * di + bb[i], 0.f);
    }

    // fused gemm2 over the wave's 8 rows
    for (int r = 0; r < 8; ++r) {
        const int rr = rbase + r;
        if (rr >= N) break;
        float o[4] = {0.f, 0.f, 0.f, 0.f};
#pragma unroll
        for (int j = 0; j < 16; j++) {
            const int    k    = eg2 * 16 + j;
            const int    srcl = r * 8 + eg2 * 2 + (j >> 3);
            const float  hk   = __shfl(h[j & 7], srcl);
            const float4 wr   = *(const float4*)&w2s[k * 64 + cq * 4];
            o[0] += hk * wr.x;
            o[1] += hk * wr.y;
            o[2] += hk * wr.z;
            o[3] += hk * wr.w;
        }
#pragma unroll
        for (int off = 16; off <= 32; off <<= 1)
#pragma unroll
            for (int i = 0; i < 4; i++) o[i] += __shfl_xor(o[i], off);

        if (eg2 == 0) {
            ushort4 ob;
            ob.x = f2bf(o[0]); ob.y = f2bf(o[1]);
            ob.z = f2bf(o[2]); ob.w = f2bf(o[3]);
            *(ushort4*)&hw[(size_t)rr * 64 + cq * 4] = ob;
        }
    }
}

// ---------------- layer 2: oct-row pull-agg + bias + log_softmax -> fp32 out -------
// softmax max/sum reduces are group-local (off=1,2,4), so they drop straight into
// the group-per-row layout; every group writes its own row (32 B per lane).

__global__ __launch_bounds__(256) void agg_l2(const unsigned short* __restrict__ B,
                                              const int2* __restrict__ csrw,
                                              const int* __restrict__ ptr,
                                              const float* __restrict__ dis,
                                              const float* __restrict__ b2,
                                              float* __restrict__ out, int N) {
    const int wid  = threadIdx.x >> 6;
    const int lane = threadIdx.x & 63;
    const int eg   = lane >> 3;
    const int co   = lane & 7;

    const int  row = blockIdx.x * 32 + wid * 8 + eg;
    const bool hr  = (row < N);

    const int   s0 = hr ? ptr[row] : 0;
    const int   s1 = hr ? ptr[row + 1] : 0;
    const float di = hr ? dis[row] : 0.f;
    const int   iters = (s1 - s0 + 7) >> 3;

    float acc[8] = {};
    gather8_oct(B, csrw, s0, s1, iters, lane, co, acc);

    if (!hr) return;

    uint4 us = *(const uint4*)&B[(size_t)row * 64 + co * 8];
    float bs[8];
    bf8_unpack(us, bs);
    float bb[8];
    *(float4*)&bb[0] = *(const float4*)&b2[co * 8];
    *(float4*)&bb[4] = *(const float4*)&b2[co * 8 + 4];

    float v[8];
#pragma unroll
    for (int i = 0; i < 8; i++) v[i] = (acc[i] + bs[i] * di) * di + bb[i];

    float m = v[0];
#pragma unroll
    for (int i = 1; i < 8; i++) m = fmaxf(m, v[i]);
#pragma unroll
    for (int off = 1; off <= 4; off <<= 1) m = fmaxf(m, __shfl_xor(m, off));
    float s = 0.f;
#pragma unroll
    for (int i = 0; i < 8; i++) s += __expf(v[i] - m);
#pragma unroll
    for (int off = 1; off <= 4; off <<= 1) s += __shfl_xor(s, off);
    float lse = m + __logf(s);

    float4 oa = make_float4(v[0] - lse, v[1] - lse, v[2] - lse, v[3] - lse);
    float4 ob = make_float4(v[4] - lse, v[5] - lse, v[6] - lse, v[7] - lse);
    *(float4*)&out[(size_t)row * 64 + co * 8]     = oa;
    *(float4*)&out[(size_t)row * 64 + co * 8 + 4] = ob;
}

// ---------------- launch ----------------

extern "C" void kernel_launch(void* const* d_in, const int* in_sizes, int n_in,
                              void* d_out, int out_size, void* d_ws, size_t ws_size,
                              hipStream_t stream) {
    const float* x   = (const float*)d_in[0];
    const int*   ei  = (const int*)d_in[1];
    const float* W1  = (const float*)d_in[2];
    const float* b1  = (const float*)d_in[3];
    const float* W2  = (const float*)d_in[4];
    const float* b2  = (const float*)d_in[5];
    float*       out = (float*)d_out;

    const int  N   = in_sizes[0] / 128;
    const int  E   = in_sizes[1] / 2;
    const int* src = ei;
    const int* dst = ei + E;
    const int  NB  = (N + 1023) / 1024;

    int shift = 9;
    while (((N - 1) >> shift) >= 256) shift++;
    const int NBUCK = ((N - 1) >> shift) + 1;
    const int CAP   = ((E / NBUCK) * 3 / 2 + 255) & ~255;

    auto align256 = [](size_t v) { return (v + 255) & ~(size_t)255; };
    char*           p        = (char*)d_ws;
    float*          dis      = (float*)p;          p += align256((size_t)N * 4);
    int*            ptr      = (int*)p;            p += align256((size_t)(N + 1) * 4);
    int*            hist     = (int*)p;            p += align256((size_t)N * 4);
    int*            partials = (int*)p;            p += align256((size_t)NB * 4);
    int*            bcur     = (int*)p;            p += align256(256 * 4);
    int2*           csrw     = (int2*)p;           p += align256((size_t)E * 8);
    int2*           bbuf     = (int2*)p;           p += align256((size_t)NBUCK * CAP * 8);
    unsigned short* xwb      = (unsigned short*)p; p += align256((size_t)N * 64 * 2);
    unsigned short* hwb      = (unsigned short*)p; p += align256((size_t)N * 64 * 2);

    bcur_init<<<1, 256, 0, stream>>>(bcur, NBUCK, CAP);
    passA<<<(E + PASSA_EDGES - 1) / PASSA_EDGES, 256, 0, stream>>>(src, dst, bcur, bbuf, E, CAP, shift);
    hist_dis<<<NBUCK, 256, 0, stream>>>(bbuf, bcur, hist, dis, N, CAP, shift);
    scan_partial<<<NB, 256, 0, stream>>>(hist, partials, N);
    scan_offsets<<<1, 256, 0, stream>>>(partials, NB);
    scan_apply<<<NB, 256, 0, stream>>>(hist, partials, ptr, N);
    passB<<<NBUCK, 256, 0, stream>>>(bbuf, bcur, ptr, csrw, dis, N, CAP, shift);

    gemm64_bf16<128><<<(N + 63) / 64, 256, 0, stream>>>(x, W1, xwb, N);
    agg_l1<<<(N + 31) / 32, 256, 0, stream>>>(xwb, csrw, ptr, dis, b1, W2, hwb, N);
    agg_l2<<<(N + 31) / 32, 256, 0, stream>>>(hwb, csrw, ptr, dis, b2, out, N);
}

// Round 3
// 285.924 us; speedup vs baseline: 1.1624x; 1.0124x over previous
//
#include <hip/hip_runtime.h>
#include <cstdint>
#include <cstddef>

#define PASSA_EDGES 8192
#define PASSB_CAP   12288   // LDS csr-image capacity (ints); padded max bucket ~10.5k for this input

// ---------------- bf16 helpers ----------------

__device__ __forceinline__ unsigned short f2bf(float f) {  // RNE
    unsigned int u = __float_as_uint(f);
    u += 0x7FFFu + ((u >> 16) & 1u);
    return (unsigned short)(u >> 16);
}

// fma 8 bf16 (packed in uint4) * w into acc[8]
__device__ __forceinline__ void bf8_fma(uint4 u, float w, float* acc) {
    acc[0] += __uint_as_float(u.x << 16) * w;
    acc[1] += __uint_as_float(u.x & 0xFFFF0000u) * w;
    acc[2] += __uint_as_float(u.y << 16) * w;
    acc[3] += __uint_as_float(u.y & 0xFFFF0000u) * w;
    acc[4] += __uint_as_float(u.z << 16) * w;
    acc[5] += __uint_as_float(u.z & 0xFFFF0000u) * w;
    acc[6] += __uint_as_float(u.w << 16) * w;
    acc[7] += __uint_as_float(u.w & 0xFFFF0000u) * w;
}
__device__ __forceinline__ void bf8_unpack(uint4 u, float* v) {
    v[0] = __uint_as_float(u.x << 16);
    v[1] = __uint_as_float(u.x & 0xFFFF0000u);
    v[2] = __uint_as_float(u.y << 16);
    v[3] = __uint_as_float(u.y & 0xFFFF0000u);
    v[4] = __uint_as_float(u.z << 16);
    v[5] = __uint_as_float(u.z & 0xFFFF0000u);
    v[6] = __uint_as_float(u.w << 16);
    v[7] = __uint_as_float(u.w & 0xFFFF0000u);
}

// ---------------- bucket cursor init ----------------

__global__ void bcur_init(int* __restrict__ bcur, int NBUCK, int CAP) {
    int b = threadIdx.x;
    if (b < NBUCK) bcur[b] = b * CAP;
}

// ---------------- pass A: bin (src,dst) by coarse dst bucket into slabs ----------------

__global__ __launch_bounds__(256) void passA(const int* __restrict__ src,
                                             const int* __restrict__ dst,
                                             int* __restrict__ bcur,
                                             int2* __restrict__ bbuf, int E,
                                             int CAP, int shift) {
    __shared__ int2 bins[PASSA_EDGES];
    __shared__ int  cnt[256], off[256], cur[256], gbase[256];
    const int t  = threadIdx.x;
    const int e0 = blockIdx.x * PASSA_EDGES;
    const int n  = min(PASSA_EDGES, E - e0);

    cnt[t] = 0;
    __syncthreads();
    for (int i = t; i < n; i += 256) atomicAdd(&cnt[dst[e0 + i] >> shift], 1);
    __syncthreads();

    int v = cnt[t];
    off[t] = v;
    __syncthreads();
    for (int o = 1; o < 256; o <<= 1) {
        int u = (t >= o) ? off[t - o] : 0;
        __syncthreads();
        off[t] += u;
        __syncthreads();
    }
    int excl = off[t] - v;
    off[t]   = excl;
    cur[t]   = excl;
    __syncthreads();

    for (int i = t; i < n; i += 256) {
        int d = dst[e0 + i];
        int s = src[e0 + i];
        int p = atomicAdd(&cur[d >> shift], 1);
        bins[p] = make_int2(s, d);
    }
    if (cnt[t] > 0) gbase[t] = atomicAdd(&bcur[t], cnt[t]);
    __syncthreads();

    const int w = t >> 6, lane = t & 63;
    for (int b = w; b < 256; b += 4) {
        int c = cnt[b];
        if (c == 0) continue;
        int lo  = off[b], go = gbase[b];
        int lim = (b + 1) * CAP;
        if (go + c > lim) c = max(0, lim - go);
        for (int i = lane; i < c; i += 64) bbuf[go + i] = bins[lo + i];
    }
}

// ---------------- per-bucket histogram + dis ----------------
// hist holds the 8-PADDED degree (slab quantum for the shuffle-free gather);
// dis uses the true degree.

__global__ __launch_bounds__(256) void hist_dis(const int2* __restrict__ bbuf,
                                                const int* __restrict__ bcur,
                                                int* __restrict__ hist,
                                                float* __restrict__ dis,
                                                int N, int CAP, int shift) {
    __shared__ int cnt[1024];
    const int b     = blockIdx.x;
    const int node0 = b << shift;
    const int nn    = min(1 << shift, N - node0);
    for (int j = threadIdx.x; j < nn; j += 256) cnt[j] = 0;
    __syncthreads();
    const int start = b * CAP, end = bcur[b];
    for (int e = start + threadIdx.x; e < end; e += 256)
        atomicAdd(&cnt[bbuf[e].y - node0], 1);
    __syncthreads();
    for (int j = threadIdx.x; j < nn; j += 256) {
        int c = cnt[j];
        hist[node0 + j] = (c + 7) & ~7;            // padded slab size
        dis[node0 + j]  = rsqrtf((float)(c + 1));  // +1 self loop (true degree)
    }
}

// ---------------- 3-phase exclusive scan hist[0..N) -> ptr[0..N] ----------------

__global__ __launch_bounds__(256) void scan_partial(const int* __restrict__ hist,
                                                    int* __restrict__ partials, int N) {
    __shared__ int red[256];
    const int t    = threadIdx.x;
    const int base = blockIdx.x * 1024 + t * 4;
    int s = 0;
    if (base + 3 < N) {
        int4 v = *(const int4*)&hist[base];
        s = v.x + v.y + v.z + v.w;
    } else {
        for (int i = 0; i < 4; i++)
            if (base + i < N) s += hist[base + i];
    }
    red[t] = s;
    __syncthreads();
    for (int off = 128; off; off >>= 1) {
        if (t < off) red[t] += red[t + off];
        __syncthreads();
    }
    if (t == 0) partials[blockIdx.x] = red[0];
}

__global__ __launch_bounds__(256) void scan_offsets(int* __restrict__ partials, int NB) {
    __shared__ int tmp[256];
    const int t = threadIdx.x;
    int v = (t < NB) ? partials[t] : 0;
    tmp[t] = v;
    __syncthreads();
    for (int off = 1; off < 256; off <<= 1) {
        int u = (t >= off) ? tmp[t - off] : 0;
        __syncthreads();
        tmp[t] += u;
        __syncthreads();
    }
    if (t < NB) partials[t] = tmp[t] - v;
}

__global__ __launch_bounds__(256) void scan_apply(const int* __restrict__ hist,
                                                  const int* __restrict__ partials,
                                                  int* __restrict__ ptr, int N) {
    __shared__ int tsum[256];
    const int t    = threadIdx.x;
    const int base = blockIdx.x * 1024 + t * 4;
    int v[4];
    int s = 0;
    for (int i = 0; i < 4; i++) {
        v[i] = (base + i < N) ? hist[base + i] : 0;
        s += v[i];
    }
    tsum[t] = s;
    __syncthreads();
    for (int off = 1; off < 256; off <<= 1) {
        int u = (t >= off) ? tsum[t - off] : 0;
        __syncthreads();
        tsum[t] += u;
        __syncthreads();
    }
    int run = partials[blockIdx.x] + tsum[t] - s;
    for (int i = 0; i < 4; i++) {
        if (base + i < N) {
            ptr[base + i] = run;
            run += v[i];
        }
    }
    if (base <= N - 1 && N - 1 < base + 4) ptr[N] = run;  // total = padded E
}

// ---------------- pass B: per-bucket LDS scatter -> padded (src,w) csr write -------
// csrw[e] = {src, bitcast(dis[src])}; pad slots (up to 7 per row) = {0, 0.0f}:
// they load row 0 (L1-hot) and fma by 0 in the gather -- branch-free slop.

__global__ __launch_bounds__(256) void passB(const int2* __restrict__ bbuf,
                                             const int* __restrict__ bcur,
                                             const int* __restrict__ ptr,
                                             int2* __restrict__ csrw,
                                             const float* __restrict__ dis,
                                             int N, int CAP, int shift) {
    __shared__ int lcnt[1024];
    __shared__ int lcsr[PASSB_CAP];
    const int b     = blockIdx.x;
    const int node0 = b << shift;
    const int nn    = min(1 << shift, N - node0);
    const int cbase = ptr[node0];
    const int csize = ptr[node0 + nn] - cbase;   // padded size

    for (int j = threadIdx.x; j < nn; j += 256) lcnt[j] = ptr[node0 + j] - cbase;
    __syncthreads();

    const int start = b * CAP, end = bcur[b];
    if (csize <= PASSB_CAP) {
        for (int i = threadIdx.x; i < csize; i += 256) lcsr[i] = -1;  // pad marker
        __syncthreads();
        for (int e = start + threadIdx.x; e < end; e += 256) {
            int2 pr = bbuf[e];
            int  p  = atomicAdd(&lcnt[pr.y - node0], 1);
            lcsr[p] = pr.x;
        }
        __syncthreads();
        for (int i = threadIdx.x; i < csize; i += 256) {
            int s = lcsr[i];
            csrw[cbase + i] = (s < 0) ? make_int2(0, 0)
                                      : make_int2(s, __float_as_int(dis[s]));
        }
    } else {  // fallback: default-fill then direct global scatter
        for (int i = threadIdx.x; i < csize; i += 256) csrw[cbase + i] = make_int2(0, 0);
        __syncthreads();
        for (int e = start + threadIdx.x; e < end; e += 256) {
            int2 pr = bbuf[e];
            int  p  = atomicAdd(&lcnt[pr.y - node0], 1);
            csrw[cbase + p] = make_int2(pr.x, __float_as_int(dis[pr.x]));
        }
    }
}

// ---------------- GEMM: Yb[N x 64](bf16) = X[N x K](f32) @ W[K x 64] ---------------
// #pragma unroll 2 REQUIRED (full unroll -> 256 VGPR + scratch spill, R6).
// Also instantiated with K=64 as the de-fused gemm2 (h f32 -> h2 bf16).

template <int K>
__global__ __launch_bounds__(256) void gemm64_bf16(const float* __restrict__ X,
                                                   const float* __restrict__ W,
                                                   unsigned short* __restrict__ Yb, int N) {
    constexpr int LDX = K + 4;
    __shared__ float xs[64 * LDX];
    __shared__ float ws[K * 64];
    const int tid  = threadIdx.x;
    const int row0 = blockIdx.x * 64;

    const float4* W4 = (const float4*)W;
    for (int i = tid; i < K * 16; i += 256) ((float4*)ws)[i] = W4[i];

    const float4* X4  = (const float4*)(X + (size_t)row0 * K);
    const int     nf4 = (row0 < N ? min(64, N - row0) : 0) * (K / 4);
    for (int i = tid; i < 16 * K; i += 256) {
        float4 v = make_float4(0.f, 0.f, 0.f, 0.f);
        if (i < nf4) v = X4[i];
        int r  = i / (K / 4);
        int kk = (i % (K / 4)) * 4;
        *(float4*)&xs[r * LDX + kk] = v;
    }
    __syncthreads();

    const int cg = tid & 15;
    const int rg = tid >> 4;

    float acc[4][4] = {};
#pragma unroll 2
    for (int k = 0; k < K; k += 4) {
        float4 xf[4], wf[4];
#pragma unroll
        for (int i = 0; i < 4; i++) xf[i] = *(const float4*)&xs[(rg * 4 + i) * LDX + k];
#pragma unroll
        for (int j = 0; j < 4; j++) wf[j] = *(const float4*)&ws[(k + j) * 64 + cg * 4];
#pragma unroll
        for (int i = 0; i < 4; i++) {
            float4 xv = xf[i];
            acc[i][0] += xv.x * wf[0].x + xv.y * wf[1].x + xv.z * wf[2].x + xv.w * wf[3].x;
            acc[i][1] += xv.x * wf[0].y + xv.y * wf[1].y + xv.z * wf[2].y + xv.w * wf[3].y;
            acc[i][2] += xv.x * wf[0].z + xv.y * wf[1].z + xv.z * wf[2].z + xv.w * wf[3].z;
            acc[i][3] += xv.x * wf[0].w + xv.y * wf[1].w + xv.z * wf[2].w + xv.w * wf[3].w;
        }
    }

#pragma unroll
    for (int i = 0; i < 4; i++) {
        int r = row0 + rg * 4 + i;
        if (r < N) {
            ushort4 o;
            o.x = f2bf(acc[i][0]); o.y = f2bf(acc[i][1]);
            o.z = f2bf(acc[i][2]); o.w = f2bf(acc[i][3]);
            *(ushort4*)&Yb[(size_t)r * 64 + cg * 4] = o;
        }
    }
}

// ---------------- shuffle-free oct-row gather: 8 rows/wave, group-per-row ----------
// Row slabs are 8-padded (s0 % 8 == 0), so each lane loads its group's whole
// (src,w) chunk directly as 4 x int4 (64B, all 8 group lanes hit the same L1
// lines -> broadcast). No ds_bpermute, no bounds predication in the loop.
// Next chunk is prefetched one iteration ahead; 8 independent B-row loads are
// in flight per lane per iteration. Groups exit independently (divergence safe).

__device__ __forceinline__ void gather8_pad(const unsigned short* __restrict__ B,
                                            const int2* __restrict__ csrw,
                                            int s0, int iters, int co, float* acc) {
    const int4* cs = (const int4*)(csrw + s0);  // 64B-aligned (s0 % 8 == 0)
    int4 c0 = make_int4(0, 0, 0, 0), c1 = c0, c2 = c0, c3 = c0;
    if (iters > 0) { c0 = cs[0]; c1 = cs[1]; c2 = cs[2]; c3 = cs[3]; }
    for (int it = 0; it < iters; ++it) {
        const int nb = min(it + 1, iters - 1) * 4;   // prefetch next chunk (clamped)
        int4 n0 = cs[nb], n1 = cs[nb + 1], n2 = cs[nb + 2], n3 = cs[nb + 3];
        uint4 u0 = *(const uint4*)&B[(size_t)c0.x * 64 + co * 8];
        uint4 u1 = *(const uint4*)&B[(size_t)c0.z * 64 + co * 8];
        uint4 u2 = *(const uint4*)&B[(size_t)c1.x * 64 + co * 8];
        uint4 u3 = *(const uint4*)&B[(size_t)c1.z * 64 + co * 8];
        uint4 u4 = *(const uint4*)&B[(size_t)c2.x * 64 + co * 8];
        uint4 u5 = *(const uint4*)&B[(size_t)c2.z * 64 + co * 8];
        uint4 u6 = *(const uint4*)&B[(size_t)c3.x * 64 + co * 8];
        uint4 u7 = *(const uint4*)&B[(size_t)c3.z * 64 + co * 8];
        bf8_fma(u0, __int_as_float(c0.y), acc);
        bf8_fma(u1, __int_as_float(c0.w), acc);
        bf8_fma(u2, __int_as_float(c1.y), acc);
        bf8_fma(u3, __int_as_float(c1.w), acc);
        bf8_fma(u4, __int_as_float(c2.y), acc);
        bf8_fma(u5, __int_as_float(c2.w), acc);
        bf8_fma(u6, __int_as_float(c3.y), acc);
        bf8_fma(u7, __int_as_float(c3.w), acc);
        c0 = n0; c1 = n1; c2 = n2; c3 = n3;
    }
}

// ---------------- layer 1: pure gather + relu -> f32 h (scratch = d_out) -----------
// De-fused: no W2 tail, no LDS. gemm2 runs as a standalone tiled kernel after.

__global__ __launch_bounds__(256) void agg_l1(const unsigned short* __restrict__ B,
                                              const int2* __restrict__ csrw,
                                              const int* __restrict__ ptr,
                                              const float* __restrict__ dis,
                                              const float* __restrict__ b1,
                                              float* __restrict__ hs, int N) {
    const int wid  = threadIdx.x >> 6;
    const int lane = threadIdx.x & 63;
    const int eg   = lane >> 3;
    const int co   = lane & 7;

    const int  row = blockIdx.x * 32 + wid * 8 + eg;   // group eg owns this row
    const bool hr  = (row < N);

    const int   s0 = hr ? ptr[row] : 0;
    const int   s1 = hr ? ptr[row + 1] : 0;
    const float di = hr ? dis[row] : 0.f;
    const int   iters = (s1 - s0) >> 3;   // slabs are 8-padded

    float acc[8] = {};
    gather8_pad(B, csrw, s0, iters, co, acc);

    if (!hr) return;

    uint4 us = *(const uint4*)&B[(size_t)row * 64 + co * 8];
    float bs[8];
    bf8_unpack(us, bs);
    float bb[8];
    *(float4*)&bb[0] = *(const float4*)&b1[co * 8];
    *(float4*)&bb[4] = *(const float4*)&b1[co * 8 + 4];

    float h[8];
#pragma unroll
    for (int i = 0; i < 8; i++)
        h[i] = fmaxf((acc[i] + bs[i] * di) * di + bb[i], 0.f);

    *(float4*)&hs[(size_t)row * 64 + co * 8]     = make_float4(h[0], h[1], h[2], h[3]);
    *(float4*)&hs[(size_t)row * 64 + co * 8 + 4] = make_float4(h[4], h[5], h[6], h[7]);
}

// ---------------- layer 2: gather h2 + bias + log_softmax -> fp32 out --------------

__global__ __launch_bounds__(256) void agg_l2(const unsigned short* __restrict__ B,
                                              const int2* __restrict__ csrw,
                                              const int* __restrict__ ptr,
                                              const float* __restrict__ dis,
                                              const float* __restrict__ b2,
                                              float* __restrict__ out, int N) {
    const int wid  = threadIdx.x >> 6;
    const int lane = threadIdx.x & 63;
    const int eg   = lane >> 3;
    const int co   = lane & 7;

    const int  row = blockIdx.x * 32 + wid * 8 + eg;
    const bool hr  = (row < N);

    const int   s0 = hr ? ptr[row] : 0;
    const int   s1 = hr ? ptr[row + 1] : 0;
    const float di = hr ? dis[row] : 0.f;
    const int   iters = (s1 - s0) >> 3;

    float acc[8] = {};
    gather8_pad(B, csrw, s0, iters, co, acc);

    if (!hr) return;

    uint4 us = *(const uint4*)&B[(size_t)row * 64 + co * 8];
    float bs[8];
    bf8_unpack(us, bs);
    float bb[8];
    *(float4*)&bb[0] = *(const float4*)&b2[co * 8];
    *(float4*)&bb[4] = *(const float4*)&b2[co * 8 + 4];

    float v[8];
#pragma unroll
    for (int i = 0; i < 8; i++) v[i] = (acc[i] + bs[i] * di) * di + bb[i];

    float m = v[0];
#pragma unroll
    for (int i = 1; i < 8; i++) m = fmaxf(m, v[i]);
#pragma unroll
    for (int off = 1; off <= 4; off <<= 1) m = fmaxf(m, __shfl_xor(m, off));
    float s = 0.f;
#pragma unroll
    for (int i = 0; i < 8; i++) s += __expf(v[i] - m);
#pragma unroll
    for (int off = 1; off <= 4; off <<= 1) s += __shfl_xor(s, off);
    float lse = m + __logf(s);

    float4 oa = make_float4(v[0] - lse, v[1] - lse, v[2] - lse, v[3] - lse);
    float4 ob = make_float4(v[4] - lse, v[5] - lse, v[6] - lse, v[7] - lse);
    *(float4*)&out[(size_t)row * 64 + co * 8]     = oa;
    *(float4*)&out[(size_t)row * 64 + co * 8 + 4] = ob;
}

// ---------------- launch ----------------

extern "C" void kernel_launch(void* const* d_in, const int* in_sizes, int n_in,
                              void* d_out, int out_size, void* d_ws, size_t ws_size,
                              hipStream_t stream) {
    const float* x   = (const float*)d_in[0];
    const int*   ei  = (const int*)d_in[1];
    const float* W1  = (const float*)d_in[2];
    const float* b1  = (const float*)d_in[3];
    const float* W2  = (const float*)d_in[4];
    const float* b2  = (const float*)d_in[5];
    float*       out = (float*)d_out;

    const int  N   = in_sizes[0] / 128;
    const int  E   = in_sizes[1] / 2;
    const int* src = ei;
    const int* dst = ei + E;
    const int  NB  = (N + 1023) / 1024;

    int shift = 9;
    while (((N - 1) >> shift) >= 256) shift++;
    const int NBUCK = ((N - 1) >> shift) + 1;
    const int CAP   = ((E / NBUCK) * 3 / 2 + 255) & ~255;

    auto align256 = [](size_t v) { return (v + 255) & ~(size_t)255; };
    char*           p        = (char*)d_ws;
    float*          dis      = (float*)p;          p += align256((size_t)N * 4);
    int*            ptr      = (int*)p;            p += align256((size_t)(N + 1) * 4);
    int*            hist     = (int*)p;            p += align256((size_t)N * 4);
    int*            partials = (int*)p;            p += align256((size_t)NB * 4);
    int*            bcur     = (int*)p;            p += align256(256 * 4);
    int2*           csrw     = (int2*)p;           p += align256(((size_t)E + 8 * (size_t)N) * 8);
    int2*           bbuf     = (int2*)p;           p += align256((size_t)NBUCK * CAP * 8);
    unsigned short* xwb      = (unsigned short*)p; p += align256((size_t)N * 64 * 2);
    unsigned short* hwb      = (unsigned short*)p; p += align256((size_t)N * 64 * 2);

    // h (post-relu, f32) scratch lives in d_out: dead until agg_l2 overwrites it.
    float* hs = out;

    bcur_init<<<1, 256, 0, stream>>>(bcur, NBUCK, CAP);
    passA<<<(E + PASSA_EDGES - 1) / PASSA_EDGES, 256, 0, stream>>>(src, dst, bcur, bbuf, E, CAP, shift);
    hist_dis<<<NBUCK, 256, 0, stream>>>(bbuf, bcur, hist, dis, N, CAP, shift);
    scan_partial<<<NB, 256, 0, stream>>>(hist, partials, N);
    scan_offsets<<<1, 256, 0, stream>>>(partials, NB);
    scan_apply<<<NB, 256, 0, stream>>>(hist, partials, ptr, N);
    passB<<<NBUCK, 256, 0, stream>>>(bbuf, bcur, ptr, csrw, dis, N, CAP, shift);

    gemm64_bf16<128><<<(N + 63) / 64, 256, 0, stream>>>(x, W1, xwb, N);
    agg_l1<<<(N + 31) / 32, 256, 0, stream>>>(xwb, csrw, ptr, dis, b1, hs, N);
    // gemm2 de-fused: h2(bf16, reuses dead xwb) = h(f32, in d_out) @ W2
    gemm64_bf16<64><<<(N + 63) / 64, 256, 0, stream>>>(hs, W2, xwb, N);
    agg_l2<<<(N + 31) / 32, 256, 0, stream>>>(xwb, csrw, ptr, dis, b2, out, N);
}